// Round 2
// 361.770 us; speedup vs baseline: 1.0642x; 1.0642x over previous
//
#include <hip/hip_runtime.h>
#include <cmath>

// ---------------------------------------------------------------------------
// SConvNetBlock: LN1 -> SiLU -> complex-decay scan -> *sc_lin -> +res
//                -> LN2 -> FFN(GEMM+SiLU+GEMM) -> +res
// GEMMs: 8-phase deep-pipelined MFMA (T2 LDS swizzle + T3/T4 counted-vmcnt
// schedule + T5 setprio + T1 bijective XCD swizzle).
// Per K-tile: 4 quadrant phases (r0,c0)(r0,c1)(r1,c1)(r1,c0); each phase
// {ds_read frags, issue one half-tile global_load_lds into the region whose
// last ds_read completed a barrier earlier, barrier, MFMA cluster, barrier}.
// Boundary s_waitcnt vmcnt(6/5) keeps 3 half-tiles of K-tile t+2 in flight;
// never drains to 0 in the main loop.
//  GEMM1: 256x256 tile, 8 waves (2Mx4N), 128KB LDS, grid 512 (%8==0).
//  GEMM2: 256x128 tile, 8 waves (4Mx2N),  96KB LDS, grid 256 (%8==0).
// LDS swizzle: slot (row,cc) holds global chunk cc^(row&7); pre-swizzled on
// the GLOBAL side so global_load_lds dest stays linear (guide rule 21).
// ---------------------------------------------------------------------------

#define DIMD 1024
#define FFD  4096
#define BATCH 4
#define SEQL 2048
#define MROWS (BATCH*SEQL)      // 8192
#define EPSF 1e-5f
#define CHUNKS 32
#define CLEN (SEQL/CHUNKS)      // 64

typedef __attribute__((ext_vector_type(8))) _Float16 half8;
typedef __attribute__((ext_vector_type(4))) _Float16 half4;
typedef __attribute__((ext_vector_type(4))) float    floatx4;

// ---- workspace layout (bytes) ----
#define H_OFF    0u                       // h   fp32 [8192][1024]   32 MB
#define E_OFF    33554432u                // e   float2 [4][32][1024] 1 MB
#define SIN_OFF  34603008u                // sin float2 [4][32][1024] 1 MB
#define H2_OFF   35651584u                // h2  fp16 [8192][1024]   16 MB
#define W1H_OFF  52428800u                // w1h fp16 [4096][1024]    8 MB
#define W2H_OFF  60817408u                // w2h fp16 [1024][4096]    8 MB
#define Y1_OFF   69206016u                // y1  fp16 [8192][4096]   64 MB

__device__ __forceinline__ void load_lds16(const _Float16* g, _Float16* l) {
    __builtin_amdgcn_global_load_lds(
        (const __attribute__((address_space(1))) unsigned int*)g,
        (__attribute__((address_space(3))) unsigned int*)l,
        16, 0, 0);
}

__global__ __launch_bounds__(256)
void cast_f32_f16(const float* __restrict__ src, _Float16* __restrict__ dst) {
    int i = (blockIdx.x * 256 + threadIdx.x) * 4;
    float4 v = *(const float4*)(src + i);
    half4 o;
    o.x = (_Float16)v.x; o.y = (_Float16)v.y; o.z = (_Float16)v.z; o.w = (_Float16)v.w;
    *(half4*)(dst + i) = o;
}

// mode 1: out = silu(LN(x)) fp32 ;  mode 2: out = LN(x) fp16
__global__ __launch_bounds__(256)
void ln_kernel(const float* __restrict__ x, const float* __restrict__ w,
               const float* __restrict__ b, float* __restrict__ of,
               _Float16* __restrict__ oh, int mode) {
    const size_t row = blockIdx.x;
    const int tid = threadIdx.x;
    float4 v = *(const float4*)(x + row * DIMD + tid * 4);
    float s = (v.x + v.y) + (v.z + v.w);
    float q = (v.x * v.x + v.y * v.y) + (v.z * v.z + v.w * v.w);
    #pragma unroll
    for (int off = 32; off; off >>= 1) {
        s += __shfl_down(s, off, 64);
        q += __shfl_down(q, off, 64);
    }
    __shared__ float red[8];
    if (!(tid & 63)) { red[tid >> 6] = s; red[4 + (tid >> 6)] = q; }
    __syncthreads();
    s = (red[0] + red[1]) + (red[2] + red[3]);
    q = (red[4] + red[5]) + (red[6] + red[7]);
    const float mu = s * (1.f / DIMD);
    const float rs = rsqrtf(q * (1.f / DIMD) - mu * mu + EPSF);
    float4 wv = *(const float4*)(w + tid * 4);
    float4 bv = *(const float4*)(b + tid * 4);
    float o0 = (v.x - mu) * rs * wv.x + bv.x;
    float o1 = (v.y - mu) * rs * wv.y + bv.y;
    float o2 = (v.z - mu) * rs * wv.z + bv.z;
    float o3 = (v.w - mu) * rs * wv.w + bv.w;
    if (mode == 1) {
        o0 = o0 / (1.f + __expf(-o0));
        o1 = o1 / (1.f + __expf(-o1));
        o2 = o2 / (1.f + __expf(-o2));
        o3 = o3 / (1.f + __expf(-o3));
        float4 ov = {o0, o1, o2, o3};
        *(float4*)(of + row * DIMD + tid * 4) = ov;
    } else {
        half4 hv;
        hv.x = (_Float16)o0; hv.y = (_Float16)o1;
        hv.z = (_Float16)o2; hv.w = (_Float16)o3;
        *(half4*)(oh + row * DIMD + tid * 4) = hv;
    }
}

__device__ __forceinline__ void get_p(const float* pre, const float* pim, int d,
                                      float& pr, float& pi) {
    float re = pre[d], im = pim[d];
    float r = sqrtf(re * re + im * im);
    float t = tanhf(r) / fmaxf(r, 1e-30f);
    pr = re * t; pi = im * t;
}

__global__ __launch_bounds__(256)
void scan_partial(const float* __restrict__ h, const float* __restrict__ pre,
                  const float* __restrict__ pim, float2* __restrict__ e) {
    const int d = blockIdx.x * 256 + threadIdx.x;
    const int c = blockIdx.y;
    const int bb = blockIdx.z;
    float pr, pi; get_p(pre, pim, d, pr, pi);
    float sr = 0.f, si = 0.f;
    const float* hp = h + ((size_t)bb * SEQL + (size_t)c * CLEN) * DIMD + d;
    #pragma unroll 4
    for (int j = 0; j < CLEN; ++j) {
        float hv = hp[(size_t)j * DIMD];
        float nr = pr * sr - pi * si + hv;
        float ni = pr * si + pi * sr;
        sr = nr; si = ni;
    }
    e[((size_t)bb * CHUNKS + c) * DIMD + d] = make_float2(sr, si);
}

__global__ __launch_bounds__(256)
void scan_combine(const float2* __restrict__ e, const float* __restrict__ pre,
                  const float* __restrict__ pim, const float* __restrict__ lre,
                  const float* __restrict__ lim, float2* __restrict__ sv) {
    const int d = blockIdx.x * 256 + threadIdx.x;
    const int bb = blockIdx.y;
    float pr, pi; get_p(pre, pim, d, pr, pi);
    float qr = pr, qi = pi;                 // p^64 via 6 squarings
    #pragma unroll
    for (int s = 0; s < 6; ++s) {
        float nr = qr * qr - qi * qi;
        float ni = 2.f * qr * qi;
        qr = nr; qi = ni;
    }
    float sr = lre[d], si = lim[d];
    for (int c = 0; c < CHUNKS; ++c) {
        sv[((size_t)bb * CHUNKS + c) * DIMD + d] = make_float2(sr, si);
        float2 ec = e[((size_t)bb * CHUNKS + c) * DIMD + d];
        float nr = qr * sr - qi * si + ec.x;
        float ni = qr * si + qi * sr + ec.y;
        sr = nr; si = ni;
    }
}

__global__ __launch_bounds__(256)
void scan_final(const float* __restrict__ h, const float* __restrict__ x,
                const float* __restrict__ pre, const float* __restrict__ pim,
                const float* __restrict__ sc, const float2* __restrict__ sv,
                float* __restrict__ x2) {
    const int d = blockIdx.x * 256 + threadIdx.x;
    const int c = blockIdx.y;
    const int bb = blockIdx.z;
    float pr, pi; get_p(pre, pim, d, pr, pi);
    float2 s0 = sv[((size_t)bb * CHUNKS + c) * DIMD + d];
    float sr = s0.x, si = s0.y;
    const float scd = sc[d];
    const size_t base = ((size_t)bb * SEQL + (size_t)c * CLEN) * DIMD + d;
    #pragma unroll 4
    for (int j = 0; j < CLEN; ++j) {
        float hv = h[base + (size_t)j * DIMD];
        float nr = pr * sr - pi * si + hv;
        float ni = pr * si + pi * sr;
        sr = nr; si = ni;
        x2[base + (size_t)j * DIMD] = x[base + (size_t)j * DIMD] + scd * sr;
    }
}

// ---------------------------------------------------------------------------
// 8-phase GEMM: C[M][N] = A[M][K] * W[N][K]^T, fp16 in, fp32 acc.
// BM=256, BK=64, 512 threads (8 waves, WM x WN).  Template BN in {256,128}.
// ---------------------------------------------------------------------------
#define MEMF asm volatile("" ::: "memory")
#define BARR do { MEMF; __builtin_amdgcn_s_barrier(); MEMF; } while (0)

template<int BN, int WM, int WN, int EPI>
__global__ __launch_bounds__(512)
void gemm8p(const _Float16* __restrict__ A, const _Float16* __restrict__ W,
            const float* __restrict__ bias, _Float16* __restrict__ out_h,
            const float* resid, float* out_f, int N, int K) {
    constexpr int BM = 256, BK = 64;
    constexpr int RC = (BM / 2) / WM;      // per-wave row-chunk (64 / 32)
    constexpr int CC = (BN / 2) / WN;      // per-wave col-chunk (32)
    constexpr int FR = RC / 16;            // row frags per chunk (4 / 2)
    constexpr int FC = CC / 16;            // col frags per chunk (2)
    constexpr int BI = BN / 128;           // B stage issues per half (2 / 1)

    __shared__ __align__(16) _Float16 As[2 * BM * BK];
    __shared__ __align__(16) _Float16 Bs[2 * BN * BK];

    const int tid  = threadIdx.x;
    const int lane = tid & 63;
    const int wave = tid >> 6;
    const int fr   = lane & 15;
    const int quad = lane >> 4;
    const int wm   = wave / WN;
    const int wn   = wave % WN;

    // T1: bijective XCD swizzle (grid sizes are multiples of 8)
    const int nx  = N / BN;
    const int nwg = nx * (MROWS / BM);
    const int lb  = blockIdx.y * gridDim.x + blockIdx.x;
    const int sid = (lb & 7) * (nwg >> 3) + (lb >> 3);
    const size_t m0 = (size_t)(sid / nx) * BM;
    const size_t n0 = (size_t)(sid % nx) * BN;

    // staging: one issue/wave = 8 rows x 64 halfs (1KB); 8 waves = 64 rows.
    // global chunk pre-swizzled: LDS slot (lane&7) <- chunk (lane&7)^(row&7).
    const int srow = lane >> 3;            // 0..7 within 8-row group
    const int gch  = (lane & 7) ^ srow;
    const _Float16* Ag = A + (m0 + (size_t)(wave * 8 + srow)) * K + gch * 8;
    const _Float16* Wg = W + (n0 + (size_t)(wave * 8 + srow)) * K + gch * 8;
    _Float16* Asl = &As[(wave * 8) * BK];  // wave-uniform LDS base
    _Float16* Bsl = &Bs[(wave * 8) * BK];

#define STAGE_A(b, kt, h) do { \
    load_lds16(Ag + (size_t)((h)*128 +  0) * K + (size_t)(kt) * BK, \
               Asl + ((b)*BM + (h)*128 +  0) * BK); \
    load_lds16(Ag + (size_t)((h)*128 + 64) * K + (size_t)(kt) * BK, \
               Asl + ((b)*BM + (h)*128 + 64) * BK); \
} while (0)

#define STAGE_B(b, kt, h) do { \
    load_lds16(Wg + (size_t)((h)*(BN/2) +  0) * K + (size_t)(kt) * BK, \
               Bsl + ((b)*BN + (h)*(BN/2) +  0) * BK); \
    if (BI == 2) \
    load_lds16(Wg + (size_t)((h)*(BN/2) + 64) * K + (size_t)(kt) * BK, \
               Bsl + ((b)*BN + (h)*(BN/2) + 64) * BK); \
} while (0)

    half8 Af[FR][2], Bf[FC][2];

#define READ_A(b, rg) do { \
    _Pragma("unroll") \
    for (int f_ = 0; f_ < FR; ++f_) { \
        const int R_ = (rg)*128 + wm*RC + f_*16 + fr; \
        _Pragma("unroll") \
        for (int ks_ = 0; ks_ < 2; ++ks_) { \
            const int slot_ = (ks_*4 + quad) ^ (fr & 7); \
            Af[f_][ks_] = *(const half8*)&As[((b)*BM + R_) * BK + slot_*8]; \
        } \
    } \
} while (0)

#define READ_B(b, cg) do { \
    _Pragma("unroll") \
    for (int j_ = 0; j_ < FC; ++j_) { \
        const int Rb_ = (cg)*(BN/2) + wn*CC + j_*16 + fr; \
        _Pragma("unroll") \
        for (int ks_ = 0; ks_ < 2; ++ks_) { \
            const int slot_ = (ks_*4 + quad) ^ (fr & 7); \
            Bf[j_][ks_] = *(const half8*)&Bs[((b)*BN + Rb_) * BK + slot_*8]; \
        } \
    } \
} while (0)

#define MM(rg, cg) do { \
    _Pragma("unroll") \
    for (int f_ = 0; f_ < FR; ++f_) \
    _Pragma("unroll") \
    for (int j_ = 0; j_ < FC; ++j_) \
    _Pragma("unroll") \
    for (int ks_ = 0; ks_ < 2; ++ks_) \
        acc[(rg)*FR + f_][(cg)*FC + j_] = __builtin_amdgcn_mfma_f32_16x16x32_f16( \
            Af[f_][ks_], Bf[j_][ks_], acc[(rg)*FR + f_][(cg)*FC + j_], 0, 0, 0); \
} while (0)

#define WAIT_STEADY do { \
    if constexpr (BN == 256) asm volatile("s_waitcnt vmcnt(6)" ::: "memory"); \
    else                     asm volatile("s_waitcnt vmcnt(5)" ::: "memory"); \
} while (0)

    floatx4 acc[2 * FR][2 * FC] = {};
    const int nt = K / BK;

    // prologue: K0 fully, K1 = {A0, B1, A1}  (FIFO order matters for vmcnt)
    STAGE_A(0, 0, 0);
    STAGE_A(0, 0, 1);
    STAGE_B(0, 0, 0);
    STAGE_B(0, 0, 1);
    STAGE_A(1, 1, 0);
    STAGE_B(1, 1, 1);
    STAGE_A(1, 1, 1);
    WAIT_STEADY;            // K0 complete; K1 partials (4+BI loads) in flight
    BARR;

    for (int t = 0; t < nt; ++t) {
        const int cur = t & 1;
        const int nxt = cur ^ 1;
        // ---- phase 0: quadrant (r0,c0); stage (t+1):B0 into idle buffer
        READ_A(cur, 0);
        READ_B(cur, 0);
        if (t + 1 < nt) STAGE_B(nxt, t + 1, 0);
        BARR;
        __builtin_amdgcn_s_setprio(1); MM(0, 0); __builtin_amdgcn_s_setprio(0);
        BARR;
        // ---- phase 1: (r0,c1); stage (t+2):A0 into region freed at phase 0
        READ_B(cur, 1);
        if (t + 2 < nt) STAGE_A(cur, t + 2, 0);
        BARR;
        __builtin_amdgcn_s_setprio(1); MM(0, 1); __builtin_amdgcn_s_setprio(0);
        BARR;
        // ---- phase 2: (r1,c1); stage (t+2):B1 into region freed at phase 1
        READ_A(cur, 1);
        if (t + 2 < nt) STAGE_B(cur, t + 2, 1);
        BARR;
        __builtin_amdgcn_s_setprio(1); MM(1, 1); __builtin_amdgcn_s_setprio(0);
        BARR;
        // ---- phase 3: (r1,c0); stage (t+2):A1 into region freed at phase 2
        READ_B(cur, 0);
        if (t + 2 < nt) STAGE_A(cur, t + 2, 1);
        BARR;
        __builtin_amdgcn_s_setprio(1); MM(1, 0); __builtin_amdgcn_s_setprio(0);
        // boundary: K-tile t+1 resident; (t+2):{A0,B1,A1} stay in flight
        if (t < nt - 2) WAIT_STEADY;
        else            asm volatile("s_waitcnt vmcnt(0)" ::: "memory");
        BARR;
    }

    // epilogue
    #pragma unroll
    for (int rg = 0; rg < 2; ++rg)
    #pragma unroll
    for (int f = 0; f < FR; ++f)
    #pragma unroll
    for (int cg = 0; cg < 2; ++cg)
    #pragma unroll
    for (int j = 0; j < FC; ++j) {
        const floatx4 a = acc[rg * FR + f][cg * FC + j];
        const size_t gn = n0 + cg * (BN / 2) + wn * CC + j * 16 + fr;
        const float bb = bias[gn];
        #pragma unroll
        for (int r = 0; r < 4; ++r) {
            const size_t gm = m0 + rg * 128 + wm * RC + f * 16 + quad * 4 + r;
            float v = a[r] + bb;
            if (EPI == 1) {
                float sl = v / (1.f + __expf(-v));
                out_h[gm * (size_t)N + gn] = (_Float16)sl;
            } else {
                out_f[gm * (size_t)N + gn] = v + resid[gm * (size_t)N + gn];
            }
        }
    }
#undef STAGE_A
#undef STAGE_B
#undef READ_A
#undef READ_B
#undef MM
#undef WAIT_STEADY
}

extern "C" void kernel_launch(void* const* d_in, const int* in_sizes, int n_in,
                              void* d_out, int out_size, void* d_ws, size_t ws_size,
                              hipStream_t stream) {
    const float* x    = (const float*)d_in[0];
    const float* ln1w = (const float*)d_in[1];
    const float* ln1b = (const float*)d_in[2];
    const float* ln2w = (const float*)d_in[3];
    const float* ln2b = (const float*)d_in[4];
    const float* sc   = (const float*)d_in[5];
    const float* pre  = (const float*)d_in[6];
    const float* pim  = (const float*)d_in[7];
    const float* lre  = (const float*)d_in[8];
    const float* lim  = (const float*)d_in[9];
    const float* w1   = (const float*)d_in[10];
    const float* b1   = (const float*)d_in[11];
    const float* w2   = (const float*)d_in[12];
    const float* b2   = (const float*)d_in[13];

    char* ws = (char*)d_ws;
    float*      h   = (float*)(ws + H_OFF);
    float2*     e   = (float2*)(ws + E_OFF);
    float2*     sv  = (float2*)(ws + SIN_OFF);
    _Float16*   h2  = (_Float16*)(ws + H2_OFF);
    _Float16*   w1h = (_Float16*)(ws + W1H_OFF);
    _Float16*   w2h = (_Float16*)(ws + W2H_OFF);
    _Float16*   y1  = (_Float16*)(ws + Y1_OFF);
    float*      x2  = (float*)d_out;
    float*      outp = (float*)d_out;

    cast_f32_f16<<<dim3(FFD * DIMD / 1024), 256, 0, stream>>>(w1, w1h);
    cast_f32_f16<<<dim3(FFD * DIMD / 1024), 256, 0, stream>>>(w2, w2h);
    ln_kernel<<<dim3(MROWS), 256, 0, stream>>>(x, ln1w, ln1b, h, nullptr, 1);
    scan_partial<<<dim3(DIMD / 256, CHUNKS, BATCH), 256, 0, stream>>>(h, pre, pim, e);
    scan_combine<<<dim3(DIMD / 256, BATCH), 256, 0, stream>>>(e, pre, pim, lre, lim, sv);
    scan_final<<<dim3(DIMD / 256, CHUNKS, BATCH), 256, 0, stream>>>(h, x, pre, pim, sc, sv, x2);
    ln_kernel<<<dim3(MROWS), 256, 0, stream>>>(x2, ln2w, ln2b, nullptr, h2, 2);
    gemm8p<256, 2, 4, 1><<<dim3(FFD / 256, MROWS / 256), 512, 0, stream>>>(
        h2, w1h, b1, y1, nullptr, nullptr, FFD, DIMD);
    gemm8p<128, 4, 2, 2><<<dim3(DIMD / 128, MROWS / 256), 512, 0, stream>>>(
        y1, w2h, b2, nullptr, x2, outp, DIMD, FFD);
}

// Round 3
// 345.160 us; speedup vs baseline: 1.1154x; 1.0481x over previous
//
#include <hip/hip_runtime.h>
#include <cmath>

// ---------------------------------------------------------------------------
// SConvNetBlock: LN1 -> SiLU -> complex-decay scan -> *sc_lin -> +res
//                -> LN2 -> FFN(GEMM+SiLU+GEMM) -> +res
// Round-3 structure:
//  * h buffer ELIMINATED: ln_stats writes (mu,rs)/row; scans recompute
//    silu(LN(x)) inline (same arithmetic, same rounding). x read once in
//    scan_final for both LN-recompute and residual.
//  * GEMM1 (8192x4096x1024): unchanged 8-phase 256x256 pipeline (A/B probe).
//  * GEMM2 (8192x1024x4096): m97-exact 128x128 tile, 32KB LDS, 4 waves,
//    ~3 blocks/CU (multi-block overlap replaces intra-block pipelining),
//    chunked XCD mapping: panel-row r -> XCD r%8 so the 8 blocks sharing an
//    A-panel (1MB, fits 4MB L2) are L2-local.
// ---------------------------------------------------------------------------

#define DIMD 1024
#define FFD  4096
#define BATCH 4
#define SEQL 2048
#define MROWS (BATCH*SEQL)      // 8192
#define EPSF 1e-5f
#define CHUNKS 32
#define CLEN (SEQL/CHUNKS)      // 64

typedef __attribute__((ext_vector_type(8))) _Float16 half8;
typedef __attribute__((ext_vector_type(4))) _Float16 half4;
typedef __attribute__((ext_vector_type(4))) float    floatx4;

// ---- workspace layout (bytes) ----
#define ST_OFF   0u                       // stats float2 [8192]     64 KB
#define E_OFF    33554432u                // e   float2 [4][32][1024] 1 MB
#define SIN_OFF  34603008u                // sin float2 [4][32][1024] 1 MB
#define H2_OFF   35651584u                // h2  fp16 [8192][1024]   16 MB
#define W1H_OFF  52428800u                // w1h fp16 [4096][1024]    8 MB
#define W2H_OFF  60817408u                // w2h fp16 [1024][4096]    8 MB
#define Y1_OFF   69206016u                // y1  fp16 [8192][4096]   64 MB

__device__ __forceinline__ void load_lds16(const _Float16* g, _Float16* l) {
    __builtin_amdgcn_global_load_lds(
        (const __attribute__((address_space(1))) unsigned int*)g,
        (__attribute__((address_space(3))) unsigned int*)l,
        16, 0, 0);
}

__global__ __launch_bounds__(256)
void cast_f32_f16(const float* __restrict__ src, _Float16* __restrict__ dst) {
    int i = (blockIdx.x * 256 + threadIdx.x) * 4;
    float4 v = *(const float4*)(src + i);
    half4 o;
    o.x = (_Float16)v.x; o.y = (_Float16)v.y; o.z = (_Float16)v.z; o.w = (_Float16)v.w;
    *(half4*)(dst + i) = o;
}

// per-row LN statistics: st[row] = (mu, rsqrt(var+eps))
__global__ __launch_bounds__(256)
void ln_stats(const float* __restrict__ x, float2* __restrict__ st) {
    const size_t row = blockIdx.x;
    const int tid = threadIdx.x;
    float4 v = *(const float4*)(x + row * DIMD + tid * 4);
    float s = (v.x + v.y) + (v.z + v.w);
    float q = (v.x * v.x + v.y * v.y) + (v.z * v.z + v.w * v.w);
    #pragma unroll
    for (int off = 32; off; off >>= 1) {
        s += __shfl_down(s, off, 64);
        q += __shfl_down(q, off, 64);
    }
    __shared__ float red[8];
    if (!(tid & 63)) { red[tid >> 6] = s; red[4 + (tid >> 6)] = q; }
    __syncthreads();
    if (tid == 0) {
        s = (red[0] + red[1]) + (red[2] + red[3]);
        q = (red[4] + red[5]) + (red[6] + red[7]);
        const float mu = s * (1.f / DIMD);
        const float rs = rsqrtf(q * (1.f / DIMD) - mu * mu + EPSF);
        st[row] = make_float2(mu, rs);
    }
}

// LN2: out fp16 = LN(x)
__global__ __launch_bounds__(256)
void ln_kernel(const float* __restrict__ x, const float* __restrict__ w,
               const float* __restrict__ b, _Float16* __restrict__ oh) {
    const size_t row = blockIdx.x;
    const int tid = threadIdx.x;
    float4 v = *(const float4*)(x + row * DIMD + tid * 4);
    float s = (v.x + v.y) + (v.z + v.w);
    float q = (v.x * v.x + v.y * v.y) + (v.z * v.z + v.w * v.w);
    #pragma unroll
    for (int off = 32; off; off >>= 1) {
        s += __shfl_down(s, off, 64);
        q += __shfl_down(q, off, 64);
    }
    __shared__ float red[8];
    if (!(tid & 63)) { red[tid >> 6] = s; red[4 + (tid >> 6)] = q; }
    __syncthreads();
    s = (red[0] + red[1]) + (red[2] + red[3]);
    q = (red[4] + red[5]) + (red[6] + red[7]);
    const float mu = s * (1.f / DIMD);
    const float rs = rsqrtf(q * (1.f / DIMD) - mu * mu + EPSF);
    float4 wv = *(const float4*)(w + tid * 4);
    float4 bv = *(const float4*)(b + tid * 4);
    half4 hv;
    hv.x = (_Float16)((v.x - mu) * rs * wv.x + bv.x);
    hv.y = (_Float16)((v.y - mu) * rs * wv.y + bv.y);
    hv.z = (_Float16)((v.z - mu) * rs * wv.z + bv.z);
    hv.w = (_Float16)((v.w - mu) * rs * wv.w + bv.w);
    *(half4*)(oh + row * DIMD + tid * 4) = hv;
}

__device__ __forceinline__ void get_p(const float* pre, const float* pim, int d,
                                      float& pr, float& pi) {
    float re = pre[d], im = pim[d];
    float r = sqrtf(re * re + im * im);
    float t = tanhf(r) / fmaxf(r, 1e-30f);
    pr = re * t; pi = im * t;
}

__device__ __forceinline__ float ln_silu(float xv, float2 st, float wd, float bd) {
    float o = (xv - st.x) * st.y * wd + bd;
    return o / (1.f + __expf(-o));
}

// per-chunk local scan (zero init) with fused LN1+SiLU recompute from x
__global__ __launch_bounds__(256)
void scan_partial(const float* __restrict__ x, const float2* __restrict__ st,
                  const float* __restrict__ lw, const float* __restrict__ lb,
                  const float* __restrict__ pre, const float* __restrict__ pim,
                  float2* __restrict__ e) {
    const int d = blockIdx.x * 256 + threadIdx.x;
    const int c = blockIdx.y;
    const int bb = blockIdx.z;
    float pr, pi; get_p(pre, pim, d, pr, pi);
    const float wd = lw[d], bd = lb[d];
    float sr = 0.f, si = 0.f;
    const size_t row0 = (size_t)bb * SEQL + (size_t)c * CLEN;
    #pragma unroll 4
    for (int j = 0; j < CLEN; ++j) {
        float xv = x[(row0 + j) * DIMD + d];
        float2 sj = st[row0 + j];
        float hv = ln_silu(xv, sj, wd, bd);
        float nr = pr * sr - pi * si + hv;
        float ni = pr * si + pi * sr;
        sr = nr; si = ni;
    }
    e[((size_t)bb * CHUNKS + c) * DIMD + d] = make_float2(sr, si);
}

// sequential combine over chunks: sv[b][c][d] = state entering chunk c
__global__ __launch_bounds__(256)
void scan_combine(const float2* __restrict__ e, const float* __restrict__ pre,
                  const float* __restrict__ pim, const float* __restrict__ lre,
                  const float* __restrict__ lim, float2* __restrict__ sv) {
    const int d = blockIdx.x * 256 + threadIdx.x;
    const int bb = blockIdx.y;
    float pr, pi; get_p(pre, pim, d, pr, pi);
    float qr = pr, qi = pi;                 // p^64 via 6 squarings
    #pragma unroll
    for (int s = 0; s < 6; ++s) {
        float nr = qr * qr - qi * qi;
        float ni = 2.f * qr * qi;
        qr = nr; qi = ni;
    }
    float sr = lre[d], si = lim[d];
    for (int c = 0; c < CHUNKS; ++c) {
        sv[((size_t)bb * CHUNKS + c) * DIMD + d] = make_float2(sr, si);
        float2 ec = e[((size_t)bb * CHUNKS + c) * DIMD + d];
        float nr = qr * sr - qi * si + ec.x;
        float ni = qr * si + qi * sr + ec.y;
        sr = nr; si = ni;
    }
}

// final scan with true incoming state; x2 = x + sc*Re(c); x read ONCE
__global__ __launch_bounds__(256)
void scan_final(const float* __restrict__ x, const float2* __restrict__ st,
                const float* __restrict__ lw, const float* __restrict__ lb,
                const float* __restrict__ pre, const float* __restrict__ pim,
                const float* __restrict__ sc, const float2* __restrict__ sv,
                float* __restrict__ x2) {
    const int d = blockIdx.x * 256 + threadIdx.x;
    const int c = blockIdx.y;
    const int bb = blockIdx.z;
    float pr, pi; get_p(pre, pim, d, pr, pi);
    const float wd = lw[d], bd = lb[d];
    float2 s0 = sv[((size_t)bb * CHUNKS + c) * DIMD + d];
    float sr = s0.x, si = s0.y;
    const float scd = sc[d];
    const size_t row0 = (size_t)bb * SEQL + (size_t)c * CLEN;
    #pragma unroll 4
    for (int j = 0; j < CLEN; ++j) {
        float xv = x[(row0 + j) * DIMD + d];
        float2 sj = st[row0 + j];
        float hv = ln_silu(xv, sj, wd, bd);
        float nr = pr * sr - pi * si + hv;
        float ni = pr * si + pi * sr;
        sr = nr; si = ni;
        x2[(row0 + j) * DIMD + d] = xv + scd * sr;
    }
}

// ---------------------------------------------------------------------------
// GEMM1: 8-phase 256x256 pipeline (UNCHANGED from round 2 — A/B probe arm).
// ---------------------------------------------------------------------------
#define MEMF asm volatile("" ::: "memory")
#define BARR do { MEMF; __builtin_amdgcn_s_barrier(); MEMF; } while (0)

template<int BN, int WM, int WN, int EPI>
__global__ __launch_bounds__(512)
void gemm8p(const _Float16* __restrict__ A, const _Float16* __restrict__ W,
            const float* __restrict__ bias, _Float16* __restrict__ out_h,
            const float* resid, float* out_f, int N, int K) {
    constexpr int BM = 256, BK = 64;
    constexpr int RC = (BM / 2) / WM;
    constexpr int CC = (BN / 2) / WN;
    constexpr int FR = RC / 16;
    constexpr int FC = CC / 16;
    constexpr int BI = BN / 128;

    __shared__ __align__(16) _Float16 As[2 * BM * BK];
    __shared__ __align__(16) _Float16 Bs[2 * BN * BK];

    const int tid  = threadIdx.x;
    const int lane = tid & 63;
    const int wave = tid >> 6;
    const int fr   = lane & 15;
    const int quad = lane >> 4;
    const int wm   = wave / WN;
    const int wn   = wave % WN;

    const int nx  = N / BN;
    const int nwg = nx * (MROWS / BM);
    const int lb  = blockIdx.y * gridDim.x + blockIdx.x;
    const int sid = (lb & 7) * (nwg >> 3) + (lb >> 3);
    const size_t m0 = (size_t)(sid / nx) * BM;
    const size_t n0 = (size_t)(sid % nx) * BN;

    const int srow = lane >> 3;
    const int gch  = (lane & 7) ^ srow;
    const _Float16* Ag = A + (m0 + (size_t)(wave * 8 + srow)) * K + gch * 8;
    const _Float16* Wg = W + (n0 + (size_t)(wave * 8 + srow)) * K + gch * 8;
    _Float16* Asl = &As[(wave * 8) * BK];
    _Float16* Bsl = &Bs[(wave * 8) * BK];

#define STAGE_A(b, kt, h) do { \
    load_lds16(Ag + (size_t)((h)*128 +  0) * K + (size_t)(kt) * BK, \
               Asl + ((b)*BM + (h)*128 +  0) * BK); \
    load_lds16(Ag + (size_t)((h)*128 + 64) * K + (size_t)(kt) * BK, \
               Asl + ((b)*BM + (h)*128 + 64) * BK); \
} while (0)

#define STAGE_B(b, kt, h) do { \
    load_lds16(Wg + (size_t)((h)*(BN/2) +  0) * K + (size_t)(kt) * BK, \
               Bsl + ((b)*BN + (h)*(BN/2) +  0) * BK); \
    if (BI == 2) \
    load_lds16(Wg + (size_t)((h)*(BN/2) + 64) * K + (size_t)(kt) * BK, \
               Bsl + ((b)*BN + (h)*(BN/2) + 64) * BK); \
} while (0)

    half8 Af[FR][2], Bf[FC][2];

#define READ_A(b, rg) do { \
    _Pragma("unroll") \
    for (int f_ = 0; f_ < FR; ++f_) { \
        const int R_ = (rg)*128 + wm*RC + f_*16 + fr; \
        _Pragma("unroll") \
        for (int ks_ = 0; ks_ < 2; ++ks_) { \
            const int slot_ = (ks_*4 + quad) ^ (fr & 7); \
            Af[f_][ks_] = *(const half8*)&As[((b)*BM + R_) * BK + slot_*8]; \
        } \
    } \
} while (0)

#define READ_B(b, cg) do { \
    _Pragma("unroll") \
    for (int j_ = 0; j_ < FC; ++j_) { \
        const int Rb_ = (cg)*(BN/2) + wn*CC + j_*16 + fr; \
        _Pragma("unroll") \
        for (int ks_ = 0; ks_ < 2; ++ks_) { \
            const int slot_ = (ks_*4 + quad) ^ (fr & 7); \
            Bf[j_][ks_] = *(const half8*)&Bs[((b)*BN + Rb_) * BK + slot_*8]; \
        } \
    } \
} while (0)

#define MM(rg, cg) do { \
    _Pragma("unroll") \
    for (int f_ = 0; f_ < FR; ++f_) \
    _Pragma("unroll") \
    for (int j_ = 0; j_ < FC; ++j_) \
    _Pragma("unroll") \
    for (int ks_ = 0; ks_ < 2; ++ks_) \
        acc[(rg)*FR + f_][(cg)*FC + j_] = __builtin_amdgcn_mfma_f32_16x16x32_f16( \
            Af[f_][ks_], Bf[j_][ks_], acc[(rg)*FR + f_][(cg)*FC + j_], 0, 0, 0); \
} while (0)

#define WAIT_STEADY do { \
    if constexpr (BN == 256) asm volatile("s_waitcnt vmcnt(6)" ::: "memory"); \
    else                     asm volatile("s_waitcnt vmcnt(5)" ::: "memory"); \
} while (0)

    floatx4 acc[2 * FR][2 * FC] = {};
    const int nt = K / BK;

    STAGE_A(0, 0, 0);
    STAGE_A(0, 0, 1);
    STAGE_B(0, 0, 0);
    STAGE_B(0, 0, 1);
    STAGE_A(1, 1, 0);
    STAGE_B(1, 1, 1);
    STAGE_A(1, 1, 1);
    WAIT_STEADY;
    BARR;

    for (int t = 0; t < nt; ++t) {
        const int cur = t & 1;
        const int nxt = cur ^ 1;
        READ_A(cur, 0);
        READ_B(cur, 0);
        if (t + 1 < nt) STAGE_B(nxt, t + 1, 0);
        BARR;
        __builtin_amdgcn_s_setprio(1); MM(0, 0); __builtin_amdgcn_s_setprio(0);
        BARR;
        READ_B(cur, 1);
        if (t + 2 < nt) STAGE_A(cur, t + 2, 0);
        BARR;
        __builtin_amdgcn_s_setprio(1); MM(0, 1); __builtin_amdgcn_s_setprio(0);
        BARR;
        READ_A(cur, 1);
        if (t + 2 < nt) STAGE_B(cur, t + 2, 1);
        BARR;
        __builtin_amdgcn_s_setprio(1); MM(1, 1); __builtin_amdgcn_s_setprio(0);
        BARR;
        READ_B(cur, 0);
        if (t + 2 < nt) STAGE_A(cur, t + 2, 1);
        BARR;
        __builtin_amdgcn_s_setprio(1); MM(1, 0); __builtin_amdgcn_s_setprio(0);
        if (t < nt - 2) WAIT_STEADY;
        else            asm volatile("s_waitcnt vmcnt(0)" ::: "memory");
        BARR;
    }

    #pragma unroll
    for (int rg = 0; rg < 2; ++rg)
    #pragma unroll
    for (int f = 0; f < FR; ++f)
    #pragma unroll
    for (int cg = 0; cg < 2; ++cg)
    #pragma unroll
    for (int j = 0; j < FC; ++j) {
        const floatx4 a = acc[rg * FR + f][cg * FC + j];
        const size_t gn = n0 + cg * (BN / 2) + wn * CC + j * 16 + fr;
        const float bb = bias[gn];
        #pragma unroll
        for (int r = 0; r < 4; ++r) {
            const size_t gm = m0 + rg * 128 + wm * RC + f * 16 + quad * 4 + r;
            float v = a[r] + bb;
            if (EPI == 1) {
                float sl = v / (1.f + __expf(-v));
                out_h[gm * (size_t)N + gn] = (_Float16)sl;
            } else {
                out_f[gm * (size_t)N + gn] = v + resid[gm * (size_t)N + gn];
            }
        }
    }
#undef STAGE_A
#undef STAGE_B
#undef READ_A
#undef READ_B
#undef MM
#undef WAIT_STEADY
}

// ---------------------------------------------------------------------------
// GEMM2: m97-exact 128x128 tile, BK=64, 256 threads / 4 waves, 32KB LDS,
// ~3 blocks/CU (reg-capped) -> multi-block overlap. Chunked XCD mapping:
// hardware block n -> XCD n%8; logical (panel-row r, col c) with r%8 == n%8
// so the 8 blocks of a panel-row (sharing a 1MB A-panel) are L2-local.
// out = A[8192x4096] * W[1024x4096]^T + bias + resid (f32).
// ---------------------------------------------------------------------------
#define G2BM 128
#define G2BN 128
#define G2BK 64

__global__ __launch_bounds__(256)
void gemm2_128(const _Float16* __restrict__ A, const _Float16* __restrict__ W,
               const float* __restrict__ bias, const float* __restrict__ resid,
               float* __restrict__ out_f, int N, int K) {
    __shared__ _Float16 As[G2BM * G2BK];
    __shared__ _Float16 Bs[G2BN * G2BK];
    const int tid  = threadIdx.x;
    const int lane = tid & 63;
    const int wave = tid >> 6;
    const int wm = (wave >> 1) * 64;
    const int wn = (wave & 1) * 64;
    // chunked XCD mapping: n -> xcd=n&7, i=n>>3; r = xcd + 8*(i>>3), c = i&7
    const int n  = blockIdx.y * gridDim.x + blockIdx.x;   // gridDim.x == 8
    const int xc = n & 7, ii = n >> 3;
    const size_t m0 = (size_t)(xc + ((ii >> 3) << 3)) * G2BM;
    const size_t n0 = (size_t)(ii & 7) * G2BN;
    const int fr = lane & 15;
    const int quad = lane >> 4;

    // staging: wave handles rows [wave*32, wave*32+32); each issue = 8 rows.
    // LDS slot (row, cc) <- global chunk cc ^ (row&7); row&7 == lane>>3.
    const int srow = wave * 32 + (lane >> 3);
    const int ccp  = ((lane & 7) ^ (lane >> 3)) * 8;
    const _Float16* ag = A + (m0 + srow) * (size_t)K + ccp;
    const _Float16* wg = W + (n0 + srow) * (size_t)K + ccp;
    _Float16* asl = &As[(wave * 32) * G2BK];
    _Float16* bsl = &Bs[(wave * 32) * G2BK];

    floatx4 acc[4][4] = {};

    for (int k0 = 0; k0 < K; k0 += G2BK) {
        #pragma unroll
        for (int t = 0; t < 4; ++t) {
            load_lds16(ag + k0 + (size_t)(t * 8) * K, asl + t * 8 * G2BK);
            load_lds16(wg + k0 + (size_t)(t * 8) * K, bsl + t * 8 * G2BK);
        }
        __syncthreads();
        #pragma unroll
        for (int kk = 0; kk < G2BK; kk += 32) {
            half8 af[4], bf[4];
            #pragma unroll
            for (int i = 0; i < 4; ++i) {
                const int slot = (((kk >> 3) + quad) ^ (fr & 7)) * 8;
                af[i] = *(const half8*)(&As[(wm + i * 16 + fr) * G2BK + slot]);
                bf[i] = *(const half8*)(&Bs[(wn + i * 16 + fr) * G2BK + slot]);
            }
            #pragma unroll
            for (int i = 0; i < 4; ++i)
                #pragma unroll
                for (int j = 0; j < 4; ++j)
                    acc[i][j] = __builtin_amdgcn_mfma_f32_16x16x32_f16(
                        af[i], bf[j], acc[i][j], 0, 0, 0);
        }
        __syncthreads();
    }

    #pragma unroll
    for (int i = 0; i < 4; ++i) {
        #pragma unroll
        for (int j = 0; j < 4; ++j) {
            #pragma unroll
            for (int r = 0; r < 4; ++r) {
                const size_t gm = m0 + wm + i * 16 + quad * 4 + r;
                const size_t gn = n0 + wn + j * 16 + fr;
                float v = acc[i][j][r] + bias[gn];
                out_f[gm * N + gn] = v + resid[gm * N + gn];
            }
        }
    }
}

extern "C" void kernel_launch(void* const* d_in, const int* in_sizes, int n_in,
                              void* d_out, int out_size, void* d_ws, size_t ws_size,
                              hipStream_t stream) {
    const float* x    = (const float*)d_in[0];
    const float* ln1w = (const float*)d_in[1];
    const float* ln1b = (const float*)d_in[2];
    const float* ln2w = (const float*)d_in[3];
    const float* ln2b = (const float*)d_in[4];
    const float* sc   = (const float*)d_in[5];
    const float* pre  = (const float*)d_in[6];
    const float* pim  = (const float*)d_in[7];
    const float* lre  = (const float*)d_in[8];
    const float* lim  = (const float*)d_in[9];
    const float* w1   = (const float*)d_in[10];
    const float* b1   = (const float*)d_in[11];
    const float* w2   = (const float*)d_in[12];
    const float* b2   = (const float*)d_in[13];

    char* ws = (char*)d_ws;
    float2*     st  = (float2*)(ws + ST_OFF);
    float2*     e   = (float2*)(ws + E_OFF);
    float2*     sv  = (float2*)(ws + SIN_OFF);
    _Float16*   h2  = (_Float16*)(ws + H2_OFF);
    _Float16*   w1h = (_Float16*)(ws + W1H_OFF);
    _Float16*   w2h = (_Float16*)(ws + W2H_OFF);
    _Float16*   y1  = (_Float16*)(ws + Y1_OFF);
    float*      x2  = (float*)d_out;
    float*      outp = (float*)d_out;

    cast_f32_f16<<<dim3(FFD * DIMD / 1024), 256, 0, stream>>>(w1, w1h);
    cast_f32_f16<<<dim3(FFD * DIMD / 1024), 256, 0, stream>>>(w2, w2h);
    ln_stats<<<dim3(MROWS), 256, 0, stream>>>(x, st);
    scan_partial<<<dim3(DIMD / 256, CHUNKS, BATCH), 256, 0, stream>>>(
        x, st, ln1w, ln1b, pre, pim, e);
    scan_combine<<<dim3(DIMD / 256, BATCH), 256, 0, stream>>>(e, pre, pim, lre, lim, sv);
    scan_final<<<dim3(DIMD / 256, CHUNKS, BATCH), 256, 0, stream>>>(
        x, st, ln1w, ln1b, pre, pim, sc, sv, x2);
    ln_kernel<<<dim3(MROWS), 256, 0, stream>>>(x2, ln2w, ln2b, h2);
    gemm8p<256, 2, 4, 1><<<dim3(FFD / 256, MROWS / 256), 512, 0, stream>>>(
        h2, w1h, b1, y1, nullptr, nullptr, FFD, DIMD);
    gemm2_128<<<dim3(DIMD / G2BN, MROWS / G2BM), 256, 0, stream>>>(
        y1, w2h, b2, x2, outp, DIMD, FFD);
}